// Round 4
// baseline (204.341 us; speedup 1.0000x reference)
//
#include <hip/hip_runtime.h>

#define QMAX 127.0f
#define BM 128
#define BN 128

typedef int int4v __attribute__((ext_vector_type(4)));

// ---------------- fused absmax for x and w -------------------------------
// No init needed: ws poison 0xAAAAAAAA is negative as signed int; abs-float
// bit patterns are non-negative ints, so atomicMax(int*) recovers the max.
__global__ void absmax2_kernel(const float4* __restrict__ px, int n4x,
                               const float4* __restrict__ pw, int n4w,
                               int gx, int* __restrict__ amax) {
    const float4* p; int n4; int* out; int nb, bid;
    if ((int)blockIdx.x < gx) { p = px; n4 = n4x; out = amax + 0; nb = gx; bid = blockIdx.x; }
    else { p = pw; n4 = n4w; out = amax + 1; nb = gridDim.x - gx; bid = blockIdx.x - gx; }
    float m = 0.f;
    int stride = nb * blockDim.x;
    for (int i = bid * blockDim.x + threadIdx.x; i < n4; i += stride) {
        float4 v = p[i];
        m = fmaxf(m, fmaxf(fmaxf(fabsf(v.x), fabsf(v.y)),
                           fmaxf(fabsf(v.z), fabsf(v.w))));
    }
    for (int off = 32; off; off >>= 1) m = fmaxf(m, __shfl_down(m, off, 64));
    __shared__ float sm[4];
    if ((threadIdx.x & 63) == 0) sm[threadIdx.x >> 6] = m;
    __syncthreads();
    if (threadIdx.x == 0) {
        float b = fmaxf(fmaxf(sm[0], sm[1]), fmaxf(sm[2], sm[3]));
        atomicMax(out, (int)__float_as_uint(b));
    }
}

// ---------------- fused quantize x and w ---------------------------------
__device__ __forceinline__ int qone(float v, float s) {
    float q = fminf(fmaxf(rintf(v / s), -QMAX), QMAX);
    return (int)q;
}
__device__ __forceinline__ int qpack4(float4 v, float s) {
    return (qone(v.x, s) & 255) | ((qone(v.y, s) & 255) << 8) |
           ((qone(v.z, s) & 255) << 16) | ((qone(v.w, s) & 255) << 24);
}

__global__ void quant2_kernel(const float4* __restrict__ sx, int4v* __restrict__ dx, int n16x,
                              const float4* __restrict__ sw, int4v* __restrict__ dw, int n16w,
                              int gx, const int* __restrict__ amax) {
    const float4* src; int4v* dst; int n16, nb, bid; float scale;
    if ((int)blockIdx.x < gx) {
        src = sx; dst = dx; n16 = n16x; nb = gx; bid = blockIdx.x;
        scale = __uint_as_float((unsigned)amax[0]) / QMAX;
    } else {
        src = sw; dst = dw; n16 = n16w; nb = gridDim.x - gx; bid = blockIdx.x - gx;
        scale = __uint_as_float((unsigned)amax[1]) / QMAX;
    }
    int stride = nb * blockDim.x;
    for (int i = bid * blockDim.x + threadIdx.x; i < n16; i += stride) {
        float4 v0 = src[4 * i + 0];
        float4 v1 = src[4 * i + 1];
        float4 v2 = src[4 * i + 2];
        float4 v3 = src[4 * i + 3];
        int4v o = { qpack4(v0, scale), qpack4(v1, scale),
                    qpack4(v2, scale), qpack4(v3, scale) };
        dst[i] = o;
    }
}

// ---------------- int8 GEMM: acc[m,n] = sum_k qx[m,k]*qw[n,k] --------------
// NO LDS, NO BARRIERS. The barrier-synchronized LDS structure plateaued at
// 46 us with every pipe idle (MfmaUtil 13%, VALU 10%, HBM 22%): the per-iter
// vmcnt(0) drain at __syncthreads is structural. Since the whole i8 working
// set (qx strip + qw) is L2-resident per XCD after the swizzle, each wave
// loads its MFMA fragments directly global->VGPR. A wave's 16x16x64 frag is
// 16 fully-consumed 64B lines (lanes L, L+16, L+32, L+48 share a line), and
// with a register double-buffer and no barrier the compiler emits
// fine-grained s_waitcnt vmcnt(N) -- the interleave the LDS loop can't do.
__global__ __launch_bounds__(256, 3) void gemm_i8_kernel(
        const char* __restrict__ qa, const char* __restrict__ qb,
        const float* __restrict__ bias, const int* __restrict__ amax,
        float* __restrict__ out, int M, int N, int K, int nbx) {
    // XCD swizzle: round-robin b%8 -> XCD; contiguous chunk of tile-space per
    // XCD so its 4MB L2 holds the working set (2MB qx strip + 1MB qw).
    const int b = blockIdx.x;
    const int chunk = gridDim.x >> 3;
    const int s = (b & 7) * chunk + (b >> 3);
    const int mt = s / nbx, nt = s % nbx;

    const int lane = threadIdx.x & 63;
    const int wid = threadIdx.x >> 6;
    const int wm = wid >> 1, wn = wid & 1;
    const int m0 = mt * BM, n0 = nt * BN;

    const int rlane = lane & 15;        // row within a 16-row group
    const int koff = (lane >> 4) << 4;  // k-chunk: 0,16,32,48

    // 4 A-pointers (m-groups) + 4 B-pointers (n-groups), advanced 64 B/slab
    const char* pa[4];
    const char* pb[4];
#pragma unroll
    for (int t = 0; t < 4; ++t) {
        pa[t] = qa + (size_t)(m0 + wm * 64 + t * 16 + rlane) * K + koff;
        pb[t] = qb + (size_t)(n0 + wn * 64 + t * 16 + rlane) * K + koff;
    }

    int4v acc[4][4];
    const int4v zero = {0, 0, 0, 0};
#pragma unroll
    for (int i = 0; i < 4; ++i)
#pragma unroll
        for (int j = 0; j < 4; ++j) acc[i][j] = zero;

#define LOADF(Ab, Bb)                                   \
    do {                                                \
        _Pragma("unroll") for (int t = 0; t < 4; ++t) { \
            Ab[t] = *(const int4v*)pa[t];               \
            Bb[t] = *(const int4v*)pb[t];               \
            pa[t] += 64; pb[t] += 64;                   \
        }                                               \
    } while (0)
#define MFMAF(Ab, Bb)                                                       \
    do {                                                                    \
        _Pragma("unroll") for (int i = 0; i < 4; ++i)                       \
            _Pragma("unroll") for (int j = 0; j < 4; ++j)                   \
                acc[i][j] = __builtin_amdgcn_mfma_i32_16x16x64_i8(          \
                    Ab[i], Bb[j], acc[i][j], 0, 0, 0);                      \
    } while (0)

    int4v A0[4], B0[4], A1[4], B1[4];
    const int NI = K >> 6;  // K=1024 -> 16 slabs of 64

    LOADF(A0, B0);  // slab 0
#pragma unroll 1
    for (int k = 0; k < NI - 2; k += 2) {
        LOADF(A1, B1);   // slab k+1 in flight...
        MFMAF(A0, B0);   // ...while computing slab k (vmcnt(8) wait, not 0)
        LOADF(A0, B0);   // slab k+2
        MFMAF(A1, B1);   // slab k+1
    }
    LOADF(A1, B1);       // slab NI-1
    MFMAF(A0, B0);       // slab NI-2
    MFMAF(A1, B1);       // slab NI-1

    // dequant + bias.  C/D layout (16x16): col = lane&15, row = (lane>>4)*4 + reg
    const float sc = (__uint_as_float((unsigned)amax[0]) / QMAX) *
                     (__uint_as_float((unsigned)amax[1]) / QMAX);
    const int cbase = n0 + wn * 64 + (lane & 15);
    const int rbase = m0 + wm * 64 + ((lane >> 4) << 2);
#pragma unroll
    for (int j = 0; j < 4; ++j) {
        const int col = cbase + j * 16;
        const float bv = bias[col];
#pragma unroll
        for (int i = 0; i < 4; ++i) {
            const int row = rbase + i * 16;
#pragma unroll
            for (int r = 0; r < 4; ++r) {
                out[(size_t)(row + r) * N + col] = (float)acc[i][j][r] * sc + bv;
            }
        }
    }
}

extern "C" void kernel_launch(void* const* d_in, const int* in_sizes, int n_in,
                              void* d_out, int out_size, void* d_ws, size_t ws_size,
                              hipStream_t stream) {
    const float* x = (const float*)d_in[0];     // [M, K]
    const float* w = (const float*)d_in[1];     // [N, K] (row-major = B^T)
    const float* bias = (const float*)d_in[2];  // [N]
    float* out = (float*)d_out;

    const int xn = in_sizes[0];
    const int wn = in_sizes[1];
    const int N = in_sizes[2];
    const int K = wn / N;
    const int M = xn / K;

    int* amax = (int*)d_ws;                     // [0]=absmax(x) bits, [1]=absmax(w) bits
    char* qx = (char*)d_ws + 1024;
    char* qw = qx + (size_t)M * K;

    const int GAX = 2048, GAW = 256;
    absmax2_kernel<<<GAX + GAW, 256, 0, stream>>>(
        (const float4*)x, xn / 4, (const float4*)w, wn / 4, GAX, amax);

    const int GQX = 4096, GQW = 256;
    quant2_kernel<<<GQX + GQW, 256, 0, stream>>>(
        (const float4*)x, (int4v*)qx, xn / 16,
        (const float4*)w, (int4v*)qw, wn / 16, GQX, amax);

    const int nbx = N / BN;
    gemm_i8_kernel<<<nbx * (M / BM), 256, 0, stream>>>(qx, qw, bias, amax, out, M, N, K, nbx);
}

// Round 5
// 185.215 us; speedup vs baseline: 1.1033x; 1.1033x over previous
//
#include <hip/hip_runtime.h>

#define QMAX 127.0f
#define BM 128
#define BN 128
#define BK 64

typedef int int4v __attribute__((ext_vector_type(4)));
typedef float float4v __attribute__((ext_vector_type(4)));

// ---------------- fused absmax for x and w -------------------------------
// No init needed: ws poison 0xAAAAAAAA is negative as signed int; abs-float
// bit patterns are non-negative ints, so atomicMax(int*) recovers the max.
__global__ void absmax2_kernel(const float4* __restrict__ px, int n4x,
                               const float4* __restrict__ pw, int n4w,
                               int gx, int* __restrict__ amax) {
    const float4* p; int n4; int* out; int nb, bid;
    if ((int)blockIdx.x < gx) { p = px; n4 = n4x; out = amax + 0; nb = gx; bid = blockIdx.x; }
    else { p = pw; n4 = n4w; out = amax + 1; nb = gridDim.x - gx; bid = blockIdx.x - gx; }
    float m = 0.f;
    int stride = nb * blockDim.x;
    for (int i = bid * blockDim.x + threadIdx.x; i < n4; i += stride) {
        float4 v = p[i];
        m = fmaxf(m, fmaxf(fmaxf(fabsf(v.x), fabsf(v.y)),
                           fmaxf(fabsf(v.z), fabsf(v.w))));
    }
    for (int off = 32; off; off >>= 1) m = fmaxf(m, __shfl_down(m, off, 64));
    __shared__ float sm[4];
    if ((threadIdx.x & 63) == 0) sm[threadIdx.x >> 6] = m;
    __syncthreads();
    if (threadIdx.x == 0) {
        float b = fmaxf(fmaxf(sm[0], sm[1]), fmaxf(sm[2], sm[3]));
        atomicMax(out, (int)__float_as_uint(b));
    }
}

// ---------------- fused quantize x and w ---------------------------------
__device__ __forceinline__ int qone(float v, float s) {
    float q = fminf(fmaxf(rintf(v / s), -QMAX), QMAX);
    return (int)q;
}
__device__ __forceinline__ int qpack4(float4 v, float s) {
    return (qone(v.x, s) & 255) | ((qone(v.y, s) & 255) << 8) |
           ((qone(v.z, s) & 255) << 16) | ((qone(v.w, s) & 255) << 24);
}

__global__ void quant2_kernel(const float4* __restrict__ sx, int4v* __restrict__ dx, int n16x,
                              const float4* __restrict__ sw, int4v* __restrict__ dw, int n16w,
                              int gx, const int* __restrict__ amax) {
    const float4* src; int4v* dst; int n16, nb, bid; float scale;
    if ((int)blockIdx.x < gx) {
        src = sx; dst = dx; n16 = n16x; nb = gx; bid = blockIdx.x;
        scale = __uint_as_float((unsigned)amax[0]) / QMAX;
    } else {
        src = sw; dst = dw; n16 = n16w; nb = gridDim.x - gx; bid = blockIdx.x - gx;
        scale = __uint_as_float((unsigned)amax[1]) / QMAX;
    }
    int stride = nb * blockDim.x;
    for (int i = bid * blockDim.x + threadIdx.x; i < n16; i += stride) {
        float4 v0 = src[4 * i + 0];
        float4 v1 = src[4 * i + 1];
        float4 v2 = src[4 * i + 2];
        float4 v3 = src[4 * i + 3];
        int4v o = { qpack4(v0, scale), qpack4(v1, scale),
                    qpack4(v2, scale), qpack4(v3, scale) };
        dst[i] = o;
    }
}

// ---------------- int8 GEMM: acc[m,n] = sum_k qx[m,k]*qw[n,k] --------------
typedef const __attribute__((address_space(1))) char glob_char;
typedef __attribute__((address_space(3))) char lds_char;

__device__ __forceinline__ void gload16(const char* g, char* l) {
    __builtin_amdgcn_global_load_lds((glob_char*)g, (lds_char*)l, 16, 0, 0);
}

// LDS layout (fragment order): slot(g, q, r) = g*64 + q*16 + r   (16B chunks)
// Frag read for tile g: lane L reads slot g*64 + L -> lane-sequential, no conflicts.
// Staging satisfies global_load_lds's wave-uniform-base + lane*16 rule.
//
// MFMA operands are SWAPPED (mfma(b, a)) so each lane's 4 acc regs hold 4
// CONSECUTIVE OUTPUT COLUMNS: epilogue is 16 global_store_dwordx4 (nt) per
// wave instead of 64 scalar stores. nt keeps the 67MB out-stream from
// evicting the L2-resident qx/qw working set under still-computing blocks.
__global__ __launch_bounds__(256, 4) void gemm_i8_kernel(
        const char* __restrict__ qa, const char* __restrict__ qb,
        const float4* __restrict__ bias4, const int* __restrict__ amax,
        float* __restrict__ out, int M, int N, int K, int nbx) {
    __shared__ char sA[2][BM * BK];
    __shared__ char sB[2][BN * BK];

    // XCD swizzle: round-robin b%8 -> XCD; contiguous chunk of tile-space per
    // XCD so its 4MB L2 holds the working set (2MB qx strip + 1MB qw).
    const int b = blockIdx.x;
    const int chunk = gridDim.x >> 3;
    const int s = (b & 7) * chunk + (b >> 3);
    const int mt = s / nbx, nt = s % nbx;

    const int tid = threadIdx.x;
    const int lane = tid & 63;
    const int wid = tid >> 6;
    const int wm = wid >> 1, wn = wid & 1;
    const int m0 = mt * BM, n0 = nt * BN;

    const int L0 = tid, L1 = 256 + tid;
    const int row0 = ((L0 >> 6) << 4) + (L0 & 15);
    const int col0 = ((L0 >> 4) & 3) << 4;
    const int row1 = ((L1 >> 6) << 4) + (L1 & 15);
    const int col1 = ((L1 >> 4) & 3) << 4;

    const char* gA0 = qa + (size_t)(m0 + row0) * K + col0;
    const char* gA1 = qa + (size_t)(m0 + row1) * K + col1;
    const char* gB0 = qb + (size_t)(n0 + row0) * K + col0;
    const char* gB1 = qb + (size_t)(n0 + row1) * K + col1;

    int4v acc[4][4];  // acc[j][i]: j = n-tile, i = m-tile (swapped-operand layout)
    const int4v zero = {0, 0, 0, 0};
#pragma unroll
    for (int i = 0; i < 4; ++i)
#pragma unroll
        for (int j = 0; j < 4; ++j) acc[i][j] = zero;

    const int aoff = wm * 4 * 64 + lane;
    const int boff = wn * 4 * 64 + lane;
    const int NI = K / BK;

    // prologue: stage tile 0 into buffer 0
    gload16(gA0, sA[0] + L0 * 16);
    gload16(gA1, sA[0] + L1 * 16);
    gload16(gB0, sB[0] + L0 * 16);
    gload16(gB1, sB[0] + L1 * 16);
    gA0 += BK; gA1 += BK; gB0 += BK; gB1 += BK;

    for (int k0 = 0; k0 < NI; ++k0) {
        const int cur = k0 & 1;
        __syncthreads();  // drains stage(k0) vmcnt + prior iter's ds_reads

        if (k0 + 1 < NI) {  // prefetch tile k0+1 into the other buffer
            const int nxt = cur ^ 1;
            gload16(gA0, sA[nxt] + L0 * 16);
            gload16(gA1, sA[nxt] + L1 * 16);
            gload16(gB0, sB[nxt] + L0 * 16);
            gload16(gB1, sB[nxt] + L1 * 16);
            gA0 += BK; gA1 += BK; gB0 += BK; gB1 += BK;
        }

        const int4v* sAv = (const int4v*)sA[cur];
        const int4v* sBv = (const int4v*)sB[cur];
        int4v a[4], bfr[4];
#pragma unroll
        for (int t = 0; t < 4; ++t) {
            a[t] = sAv[aoff + t * 64];
            bfr[t] = sBv[boff + t * 64];
        }
        // swapped operands: D = mfma(B_frag, A_frag) accumulates C^T fragment:
        // lane&15 -> output ROW, (lane>>4)*4+reg -> output COL (4 consecutive)
#pragma unroll
        for (int j = 0; j < 4; ++j)
#pragma unroll
            for (int i = 0; i < 4; ++i)
                acc[j][i] = __builtin_amdgcn_mfma_i32_16x16x64_i8(bfr[j], a[i], acc[j][i], 0, 0, 0);
    }

    // dequant + bias, vectorized stores.
    const float sc = (__uint_as_float((unsigned)amax[0]) / QMAX) *
                     (__uint_as_float((unsigned)amax[1]) / QMAX);
    const int quad = lane >> 4;
    const int rbase = m0 + wm * 64 + (lane & 15);
    const int cb_e = n0 + wn * 64;                 // wave's col base (elements)
#pragma unroll
    for (int j = 0; j < 4; ++j) {
        const int colv = (cb_e >> 2) + (j << 2) + quad;   // float4 index
        const float4 bv = bias4[colv];
#pragma unroll
        for (int i = 0; i < 4; ++i) {
            const int row = rbase + i * 16;
            float4v v;
            v[0] = (float)acc[j][i][0] * sc + bv.x;
            v[1] = (float)acc[j][i][1] * sc + bv.y;
            v[2] = (float)acc[j][i][2] * sc + bv.z;
            v[3] = (float)acc[j][i][3] * sc + bv.w;
            float4v* dst = (float4v*)(out + (size_t)row * N) + colv;
            __builtin_nontemporal_store(v, dst);
        }
    }
}

extern "C" void kernel_launch(void* const* d_in, const int* in_sizes, int n_in,
                              void* d_out, int out_size, void* d_ws, size_t ws_size,
                              hipStream_t stream) {
    const float* x = (const float*)d_in[0];     // [M, K]
    const float* w = (const float*)d_in[1];     // [N, K] (row-major = B^T)
    const float* bias = (const float*)d_in[2];  // [N]
    float* out = (float*)d_out;

    const int xn = in_sizes[0];
    const int wn = in_sizes[1];
    const int N = in_sizes[2];
    const int K = wn / N;
    const int M = xn / K;

    int* amax = (int*)d_ws;                     // [0]=absmax(x) bits, [1]=absmax(w) bits
    char* qx = (char*)d_ws + 1024;
    char* qw = qx + (size_t)M * K;

    const int GAX = 2048, GAW = 256;
    absmax2_kernel<<<GAX + GAW, 256, 0, stream>>>(
        (const float4*)x, xn / 4, (const float4*)w, wn / 4, GAX, amax);

    const int GQX = 4096, GQW = 256;
    quant2_kernel<<<GQX + GQW, 256, 0, stream>>>(
        (const float4*)x, (int4v*)qx, xn / 16,
        (const float4*)w, (int4v*)qw, wn / 16, GQX, amax);

    const int nbx = N / BN;
    gemm_i8_kernel<<<nbx * (M / BM), 256, 0, stream>>>(
        qx, qw, (const float4*)bias, amax, out, M, N, K, nbx);
}

// Round 6
// 175.156 us; speedup vs baseline: 1.1666x; 1.0574x over previous
//
#include <hip/hip_runtime.h>

#define QMAX 127.0f

typedef int int4v __attribute__((ext_vector_type(4)));
typedef float float4v __attribute__((ext_vector_type(4)));

// ---------------- fused absmax for x and w -------------------------------
// No init needed: ws poison 0xAAAAAAAA is negative as signed int; abs-float
// bit patterns are non-negative ints, so atomicMax(int*) recovers the max.
__global__ void absmax2_kernel(const float4* __restrict__ px, int n4x,
                               const float4* __restrict__ pw, int n4w,
                               int gx, int* __restrict__ amax) {
    const float4* p; int n4; int* out; int nb, bid;
    if ((int)blockIdx.x < gx) { p = px; n4 = n4x; out = amax + 0; nb = gx; bid = blockIdx.x; }
    else { p = pw; n4 = n4w; out = amax + 1; nb = gridDim.x - gx; bid = blockIdx.x - gx; }
    float m = 0.f;
    int stride = nb * blockDim.x;
    for (int i = bid * blockDim.x + threadIdx.x; i < n4; i += stride) {
        float4 v = p[i];
        m = fmaxf(m, fmaxf(fmaxf(fabsf(v.x), fabsf(v.y)),
                           fmaxf(fabsf(v.z), fabsf(v.w))));
    }
    for (int off = 32; off; off >>= 1) m = fmaxf(m, __shfl_down(m, off, 64));
    __shared__ float sm[4];
    if ((threadIdx.x & 63) == 0) sm[threadIdx.x >> 6] = m;
    __syncthreads();
    if (threadIdx.x == 0) {
        float b = fmaxf(fmaxf(sm[0], sm[1]), fmaxf(sm[2], sm[3]));
        atomicMax(out, (int)__float_as_uint(b));
    }
}

// ---------------- fused quantize: x linear, w repacked to frag order ------
__device__ __forceinline__ int qone(float v, float s) {
    float q = fminf(fmaxf(rintf(v / s), -QMAX), QMAX);
    return (int)q;
}
__device__ __forceinline__ int qpack4(float4 v, float s) {
    return (qone(v.x, s) & 255) | ((qone(v.y, s) & 255) << 8) |
           ((qone(v.z, s) & 255) << 16) | ((qone(v.w, s) & 255) << 24);
}

// w is stored pre-packed in MFMA B-fragment order so the GEMM's B loads are
// base + lane*16 (perfectly coalesced, no LDS round-trip needed):
//   slot(g,kc,q,r) = (g*KC + kc)*64 + q*16 + r   holds qw[n=g*16+r][k=kc*64+q*16 ..+16]
__global__ void quant2_kernel(const float4* __restrict__ sx, int4v* __restrict__ dx, int n16x,
                              const float4* __restrict__ sw, int4v* __restrict__ dw, int n16w,
                              int gx, int kshift, int KC, const int* __restrict__ amax) {
    const float4* src; int n16, nb, bid; float scale; int isw;
    if ((int)blockIdx.x < gx) {
        src = sx; n16 = n16x; nb = gx; bid = blockIdx.x; isw = 0;
        scale = __uint_as_float((unsigned)amax[0]) / QMAX;
    } else {
        src = sw; n16 = n16w; nb = gridDim.x - gx; bid = blockIdx.x - gx; isw = 1;
        scale = __uint_as_float((unsigned)amax[1]) / QMAX;
    }
    int stride = nb * blockDim.x;
    for (int i = bid * blockDim.x + threadIdx.x; i < n16; i += stride) {
        float4 v0 = src[4 * i + 0];
        float4 v1 = src[4 * i + 1];
        float4 v2 = src[4 * i + 2];
        float4 v3 = src[4 * i + 3];
        int4v o = { qpack4(v0, scale), qpack4(v1, scale),
                    qpack4(v2, scale), qpack4(v3, scale) };
        if (!isw) {
            dx[i] = o;
        } else {
            int n = i >> kshift;            // row of qw
            int kg = i & ((1 << kshift) - 1);
            int kc = kg >> 2, q = kg & 3;
            int g = n >> 4, r = n & 15;
            dw[(g * KC + kc) * 64 + q * 16 + r] = o;
        }
    }
}

// ---------------- int8 GEMM: out[m,n] = sum_k qx[m,k]*qw[n,k] --------------
// BARRIER-FREE K-LOOP. R1-R5 showed the per-iter __syncthreads convoy pins
// the kernel at ~46us with every pipe ~13% busy, regardless of buffering,
// fetch path, or store shape. Here: block = 64-row strip x ALL of N (qw is
// only 1MB, L2-resident); A staged to LDS once (one barrier total); B-frags
// stream direct global->VGPR from the pre-packed qw with a register double
// buffer. Waves drift freely; compiler can use fine-grained vmcnt.
typedef const __attribute__((address_space(1))) char glob_char;
typedef __attribute__((address_space(3))) char lds_char;

__device__ __forceinline__ void gload16(const char* g, char* l) {
    __builtin_amdgcn_global_load_lds((glob_char*)g, (lds_char*)l, 16, 0, 0);
}

__global__ __launch_bounds__(512, 2) void gemm_i8_kernel(
        const char* __restrict__ qa, const char* __restrict__ qb,
        const float4* __restrict__ bias4, const int* __restrict__ amax,
        float* __restrict__ out, int M, int N, int K) {
    extern __shared__ char sA[];   // 64 rows x K bytes, frag order (64KB @ K=1024)

    const int KC = K >> 6;
    const int tid = threadIdx.x;
    const int lane = tid & 63;
    const int w = tid >> 6;          // wave 0..7, owns cols [w*128, w*128+128)
    const int m0 = blockIdx.x * 64;
    const int kb = __builtin_ctz(K); // K is a power of two here

    // ---- stage A once: slot(i,kc,q,r) = i*K + kc*64 + q*16 + r (16B units)
    const int rounds = (K >> 3) >> 2;            // 64*K/16/512 = K/128
    for (int R = 0; R < rounds; ++R) {
        const int C = R * 512 + tid;
        const int i = C >> kb;
        const int kc = (C & (K - 1)) >> 6;
        const int q = (C >> 4) & 3;
        const int r = C & 15;
        const char* src = qa + (size_t)(m0 + i * 16 + r) * K + kc * 64 + q * 16;
        gload16(src, sA + (size_t)C * 16);
    }
    __syncthreads();   // the ONLY barrier

    int4v acc[8][4];
    const int4v zero = {0, 0, 0, 0};
#pragma unroll
    for (int j = 0; j < 8; ++j)
#pragma unroll
        for (int i = 0; i < 4; ++i) acc[j][i] = zero;

    const int4v* sAv = (const int4v*)sA;
    // B frag (j, kc) for this wave: qb byte offset ((w*8+j)*KC + kc)*1024 + lane*16
    const char* bbase = qb + (size_t)(w * 8) * KC * 1024 + lane * 16;

#define LOADB(Bb, kc)                                                        \
    do { _Pragma("unroll") for (int j = 0; j < 8; ++j)                       \
        Bb[j] = *(const int4v*)(bbase + ((size_t)j * KC + (kc)) * 1024);     \
    } while (0)
#define LOADA(Af, kc)                                                        \
    do { _Pragma("unroll") for (int i = 0; i < 4; ++i)                       \
        Af[i] = sAv[i * K + (kc) * 64 + lane];                               \
    } while (0)
#define MF(Bb, Af)                                                           \
    do { _Pragma("unroll") for (int j = 0; j < 8; ++j)                       \
        _Pragma("unroll") for (int i = 0; i < 4; ++i)                        \
            acc[j][i] = __builtin_amdgcn_mfma_i32_16x16x64_i8(               \
                Bb[j], Af[i], acc[j][i], 0, 0, 0);                           \
    } while (0)

    int4v B0[8], B1[8], Af[4];
    LOADB(B0, 0);
#pragma unroll 1
    for (int kc = 0; kc + 2 < KC; kc += 2) {
        LOADB(B1, kc + 1);      // next slab in flight while computing current
        LOADA(Af, kc);
        MF(B0, Af);
        LOADB(B0, kc + 2);
        LOADA(Af, kc + 1);
        MF(B1, Af);
    }
    LOADB(B1, KC - 1);
    LOADA(Af, KC - 2);
    MF(B0, Af);
    LOADA(Af, KC - 1);
    MF(B1, Af);

    // dequant + bias. Swapped-operand C layout: lane&15 -> row, quad*4+reg -> col.
    const float sc = (__uint_as_float((unsigned)amax[0]) / QMAX) *
                     (__uint_as_float((unsigned)amax[1]) / QMAX);
    const int quad = lane >> 4;
    const int rbase = m0 + (lane & 15);
    const int cb4 = w * 32;        // float4 column base
#pragma unroll
    for (int j = 0; j < 8; ++j) {
        const float4 bv = bias4[cb4 + j * 4 + quad];
#pragma unroll
        for (int i = 0; i < 4; ++i) {
            const int row = rbase + i * 16;
            float4v v;
            v[0] = (float)acc[j][i][0] * sc + bv.x;
            v[1] = (float)acc[j][i][1] * sc + bv.y;
            v[2] = (float)acc[j][i][2] * sc + bv.z;
            v[3] = (float)acc[j][i][3] * sc + bv.w;
            *((float4v*)(out + (size_t)row * N) + cb4 + j * 4 + quad) = v;
        }
    }
}

extern "C" void kernel_launch(void* const* d_in, const int* in_sizes, int n_in,
                              void* d_out, int out_size, void* d_ws, size_t ws_size,
                              hipStream_t stream) {
    const float* x = (const float*)d_in[0];     // [M, K]
    const float* w = (const float*)d_in[1];     // [N, K] (row-major = B^T)
    const float* bias = (const float*)d_in[2];  // [N]
    float* out = (float*)d_out;

    const int xn = in_sizes[0];
    const int wn = in_sizes[1];
    const int N = in_sizes[2];
    const int K = wn / N;
    const int M = xn / K;
    const int KC = K >> 6;
    const int kshift = __builtin_ctz(K >> 4);   // 16B-groups per qw row

    int* amax = (int*)d_ws;                     // [0]=absmax(x) bits, [1]=absmax(w) bits
    char* qx = (char*)d_ws + 1024;
    char* qw = qx + (size_t)M * K;              // frag-order packed

    const int GAX = 2048, GAW = 256;
    absmax2_kernel<<<GAX + GAW, 256, 0, stream>>>(
        (const float4*)x, xn / 4, (const float4*)w, wn / 4, GAX, amax);

    const int GQX = 4096, GQW = 256;
    quant2_kernel<<<GQX + GQW, 256, 0, stream>>>(
        (const float4*)x, (int4v*)qx, xn / 16,
        (const float4*)w, (int4v*)qw, wn / 16, GQX, kshift, KC, amax);

    gemm_i8_kernel<<<M / 64, 512, 64 * K, stream>>>(
        qx, qw, (const float4*)bias, amax, out, M, N, K);
}